// Round 6
// baseline (241.104 us; speedup 1.0000x reference)
//
#include <hip/hip_runtime.h>
#include <hip/hip_bf16.h>

typedef unsigned short u16;
typedef __attribute__((ext_vector_type(8))) __bf16 bf16x8;
typedef __attribute__((ext_vector_type(4))) float f32x4;
typedef __attribute__((ext_vector_type(2))) unsigned int u32x2;

#define MODEL_DIM 1024
#define NUM_HEADS 16
#define HEAD_DIM  64
#define BATCH     4
#define SEQ       2048
#define ROWS      (BATCH*SEQ)     // 8192

static __device__ __forceinline__ u16 f2bf(float f) {
    union { __hip_bfloat16 h; u16 u; } cv;
    cv.h = __float2bfloat16(f);
    return cv.u;
}

static __device__ __forceinline__ void gload16(const u16* g, unsigned lds_byte) {
    __builtin_amdgcn_global_load_lds(
        (const __attribute__((address_space(1))) unsigned int*)g,
        (__attribute__((address_space(3))) unsigned int*)(uintptr_t)lds_byte,
        16, 0, 0);
}

// ---------------- fused cast f32 -> bf16 (x + 4 weights, contiguous out) ----
__global__ void castk_all(const float* __restrict__ x,
                          const float* __restrict__ w0, const float* __restrict__ w1,
                          const float* __restrict__ w2, const float* __restrict__ w3,
                          u16* __restrict__ out) {
    const int total = ROWS * MODEL_DIM + 4 * MODEL_DIM * MODEL_DIM;  // 12.58M
    int i = (blockIdx.x * blockDim.x + threadIdx.x) * 4;
    int stride = gridDim.x * blockDim.x * 4;
    for (; i < total; i += stride) {
        const float* src;
        int off;
        if (i < ROWS * MODEL_DIM) { src = x; off = i; }
        else {
            int j = i - ROWS * MODEL_DIM;
            int w = j >> 20;
            off = j & 1048575;
            src = (w == 0) ? w0 : (w == 1) ? w1 : (w == 2) ? w2 : w3;
        }
        float4 v = *reinterpret_cast<const float4*>(src + off);
        ushort4 o;
        o.x = f2bf(v.x); o.y = f2bf(v.y); o.z = f2bf(v.z); o.w = f2bf(v.w);
        *reinterpret_cast<ushort4*>(out + i) = o;
    }
}

// ---------------- NT GEMM core ----------------
#define BM 128
#define BN 128
#define BK 64
#define LDST 72

// fused QKV projection: grid (M/128, 24); blockIdx.y selects matrix + col block
// Q output is pre-scaled by 0.125*log2(e) (softmax scale folded out of attn).
__global__ __launch_bounds__(256) void gemm_qkv(
    const u16* __restrict__ A,
    const u16* __restrict__ Wq, const u16* __restrict__ Wk, const u16* __restrict__ Wv,
    u16* __restrict__ qO, u16* __restrict__ kO, u16* __restrict__ vO)
{
    __shared__ u16 As[BM * LDST];
    __shared__ u16 Bs[BN * LDST];
    const int t    = threadIdx.x;
    const int wid  = t >> 6;
    const int lane = t & 63;
    const int lo   = lane & 15, hi = lane >> 4;
    const int bm   = blockIdx.x * BM;
    const int mat  = blockIdx.y >> 3;
    const int bn   = (blockIdx.y & 7) * BN;
    const u16* W   = (mat == 0) ? Wq : (mat == 1) ? Wk : Wv;
    u16* outB      = (mat == 0) ? qO : (mat == 1) ? kO : vO;
    const float qscale = (mat == 0) ? 0.18033688f : 1.0f;   // 0.125*log2(e)
    const int wr   = wid >> 1, wc = wid & 1;
    const int K = MODEL_DIM;

    f32x4 acc[4][4];
#pragma unroll
    for (int m = 0; m < 4; m++)
#pragma unroll
        for (int n = 0; n < 4; n++) acc[m][n] = (f32x4){0.f, 0.f, 0.f, 0.f};

    for (int k0 = 0; k0 < K; k0 += BK) {
        __syncthreads();
#pragma unroll
        for (int i = 0; i < 4; i++) {
            int a   = t + 256 * i;
            int row = a >> 3, ch = (a & 7) * 8;
            uint4 va = *reinterpret_cast<const uint4*>(A + (size_t)(bm + row) * K + k0 + ch);
            *reinterpret_cast<uint4*>(As + row * LDST + ch) = va;
            uint4 vb = *reinterpret_cast<const uint4*>(W + (size_t)(bn + row) * K + k0 + ch);
            *reinterpret_cast<uint4*>(Bs + row * LDST + ch) = vb;
        }
        __syncthreads();
#pragma unroll
        for (int h = 0; h < 2; h++) {
            bf16x8 af[4], bfr[4];
#pragma unroll
            for (int m = 0; m < 4; m++)
                af[m] = *reinterpret_cast<const bf16x8*>(As + (wr * 64 + m * 16 + lo) * LDST + h * 32 + hi * 8);
#pragma unroll
            for (int n = 0; n < 4; n++)
                bfr[n] = *reinterpret_cast<const bf16x8*>(Bs + (wc * 64 + n * 16 + lo) * LDST + h * 32 + hi * 8);
#pragma unroll
            for (int m = 0; m < 4; m++)
#pragma unroll
                for (int n = 0; n < 4; n++)
                    acc[m][n] = __builtin_amdgcn_mfma_f32_16x16x32_bf16(af[m], bfr[n], acc[m][n], 0, 0, 0);
        }
    }

#pragma unroll
    for (int m = 0; m < 4; m++)
#pragma unroll
        for (int n = 0; n < 4; n++)
#pragma unroll
            for (int r = 0; r < 4; r++) {
                int row = bm + wr * 64 + m * 16 + hi * 4 + r;
                int col = bn + wc * 64 + n * 16 + lo;
                int b = row >> 11, np = row & 2047;
                int hh = col >> 6, dd = col & 63;
                outB[(((size_t)(b * NUM_HEADS + hh) * SEQ + np) << 6) + dd] = f2bf(acc[m][n][r] * qscale);
            }
}

// out-projection: C = A * Wo^T + bias, f32 out
__global__ __launch_bounds__(256) void gemm_out(
    const u16* __restrict__ A,
    const u16* __restrict__ W,
    float* __restrict__ outF,
    const float* __restrict__ bias)
{
    __shared__ u16 As[BM * LDST];
    __shared__ u16 Bs[BN * LDST];
    const int t    = threadIdx.x;
    const int wid  = t >> 6;
    const int lane = t & 63;
    const int lo   = lane & 15, hi = lane >> 4;
    const int bm   = blockIdx.x * BM;
    const int bn   = blockIdx.y * BN;
    const int wr   = wid >> 1, wc = wid & 1;
    const int K = MODEL_DIM, N = MODEL_DIM;

    f32x4 acc[4][4];
#pragma unroll
    for (int m = 0; m < 4; m++)
#pragma unroll
        for (int n = 0; n < 4; n++) acc[m][n] = (f32x4){0.f, 0.f, 0.f, 0.f};

    for (int k0 = 0; k0 < K; k0 += BK) {
        __syncthreads();
#pragma unroll
        for (int i = 0; i < 4; i++) {
            int a   = t + 256 * i;
            int row = a >> 3, ch = (a & 7) * 8;
            uint4 va = *reinterpret_cast<const uint4*>(A + (size_t)(bm + row) * K + k0 + ch);
            *reinterpret_cast<uint4*>(As + row * LDST + ch) = va;
            uint4 vb = *reinterpret_cast<const uint4*>(W + (size_t)(bn + row) * K + k0 + ch);
            *reinterpret_cast<uint4*>(Bs + row * LDST + ch) = vb;
        }
        __syncthreads();
#pragma unroll
        for (int h = 0; h < 2; h++) {
            bf16x8 af[4], bfr[4];
#pragma unroll
            for (int m = 0; m < 4; m++)
                af[m] = *reinterpret_cast<const bf16x8*>(As + (wr * 64 + m * 16 + lo) * LDST + h * 32 + hi * 8);
#pragma unroll
            for (int n = 0; n < 4; n++)
                bfr[n] = *reinterpret_cast<const bf16x8*>(Bs + (wc * 64 + n * 16 + lo) * LDST + h * 32 + hi * 8);
#pragma unroll
            for (int m = 0; m < 4; m++)
#pragma unroll
                for (int n = 0; n < 4; n++)
                    acc[m][n] = __builtin_amdgcn_mfma_f32_16x16x32_bf16(af[m], bfr[n], acc[m][n], 0, 0, 0);
        }
    }

#pragma unroll
    for (int m = 0; m < 4; m++)
#pragma unroll
        for (int n = 0; n < 4; n++)
#pragma unroll
            for (int r = 0; r < 4; r++) {
                int row = bm + wr * 64 + m * 16 + hi * 4 + r;
                int col = bn + wc * 64 + n * 16 + lo;
                outF[(size_t)row * N + col] = acc[m][n][r] + bias[col];
            }
}

// ---------------- flash attention v5 -------------------------------------
// 64-row q-tiles, 2048 blocks, single-buffer 16KB LDS -> 8 blocks/CU (32
// waves/CU cap). Swapped QK^T/PV, in-register softmax, tr16 V, defer-max.
// Q is pre-scaled by 0.125*log2e in gemm_qkv.

static __device__ __forceinline__ u32x2 tr16(unsigned int addr) {
    u32x2 r;
    asm volatile("ds_read_b64_tr_b16 %0, %1" : "=v"(r) : "v"(addr));
    return r;
}

__global__ __launch_bounds__(256, 8) void attn(
    const u16* __restrict__ Q,   // [B*H][N][64]
    const u16* __restrict__ Kg,
    const u16* __restrict__ Vg,
    u16* __restrict__ O)         // [B][N][H*64]
{
    // LDS (u16 elems): K swizzled @0 (4096), V subtiled @4096 (4096) = 16KB
    __shared__ u16 lds[8192];
    const int t    = threadIdx.x;
    const int wid  = t >> 6, lane = t & 63;
    const int lo   = lane & 15, hi = lane >> 4;
    const int y    = blockIdx.y;
    const int qt   = 31 - (((int)blockIdx.x + y) & 31);   // longest-first, de-correlated
    const int bh   = y;
    const size_t base = (size_t)bh * SEQ * 64;
    const int qbase = qt * 64 + wid * 16;
    const unsigned ldsb = (unsigned)(uintptr_t)lds;

    // staging: per-lane global source offsets for linear LDS dests.
    // K swizzled: LDS slot o holds K[o>>6][ ((((o&63)*2) ^ ((o>>6 & 7)<<4))) >> 1 ]
    // V subtiled: slot o holds V[(o>>11)*32 + ((o>>4)&31)][((o>>9)&3)*16 + (o&15)]
    int srcK[2], srcV[2];
    unsigned dstK[2], dstV[2];
#pragma unroll
    for (int ti = 0; ti < 2; ti++) {
        int o   = t * 8 + ti * 2048;
        int row = o >> 6;
        int colb = ((o & 63) * 2) ^ ((row & 7) << 4);
        srcK[ti] = row * 64 + (colb >> 1);
        dstK[ti] = ldsb + o * 2;
        int st = o >> 9;
        int kv = (st >> 2) * 32 + ((o >> 4) & 31);
        int d  = (st & 3) * 16 + (o & 15);
        srcV[ti] = kv * 64 + d;
        dstV[ti] = ldsb + 8192 + o * 2;
    }

    // Q fragments (B-operand): lane holds Q[qbase+lo][h*32+hi*8+..] (pre-scaled)
    bf16x8 qf[2];
#pragma unroll
    for (int h = 0; h < 2; h++)
        qf[h] = *reinterpret_cast<const bf16x8*>(Q + base + (size_t)(qbase + lo) * 64 + h * 32 + hi * 8);
    asm volatile("" : "+v"(qf[0]), "+v"(qf[1]));

    float m_run = -3.0e38f, l_part = 0.f;
    f32x4 acc[4];
#pragma unroll
    for (int dt = 0; dt < 4; dt++) acc[dt] = (f32x4){0.f, 0.f, 0.f, 0.f};

    for (int j = 0; j <= qt; j++) {
        __builtin_amdgcn_s_barrier();       // prev-iter readers done before overwrite
        {
            const u16* Kt = Kg + base + (size_t)j * 4096;
            const u16* Vt = Vg + base + (size_t)j * 4096;
#pragma unroll
            for (int ti = 0; ti < 2; ti++) {
                gload16(Kt + srcK[ti], dstK[ti]);
                gload16(Vt + srcV[ti], dstV[ti]);
            }
        }
        asm volatile("s_waitcnt vmcnt(0)" ::: "memory");
        __builtin_amdgcn_s_barrier();
        __builtin_amdgcn_sched_barrier(0);

        // S^T = K Q^T: lane holds S[q=qbase+lo][kv=j*64+kt*16+hi*4+r]
        f32x4 s[4];
#pragma unroll
        for (int kh = 0; kh < 2; kh++) {    // kt halves: caps kf live-set at 16 VGPR
            bf16x8 kfa[2][2];
#pragma unroll
            for (int k2 = 0; k2 < 2; k2++)
#pragma unroll
                for (int h = 0; h < 2; h++)
                    kfa[k2][h] = *reinterpret_cast<const bf16x8*>(
                        (const char*)lds + ((kh * 2 + k2) * 16 + lo) * 128 + ((h * 64 + hi * 16) ^ ((lo & 7) << 4)));
            __builtin_amdgcn_s_setprio(1);
#pragma unroll
            for (int k2 = 0; k2 < 2; k2++) {
                f32x4 a = (f32x4){0.f, 0.f, 0.f, 0.f};
#pragma unroll
                for (int h = 0; h < 2; h++)
                    a = __builtin_amdgcn_mfma_f32_16x16x32_bf16(kfa[k2][h], qf[h], a, 0, 0, 0);
                s[kh * 2 + k2] = a;
            }
            __builtin_amdgcn_s_setprio(0);
        }
        if (j == qt) {                       // diagonal: causal mask (local indices)
            const int ql = wid * 16 + lo;
#pragma unroll
            for (int kt = 0; kt < 4; kt++)
#pragma unroll
                for (int r = 0; r < 4; r++)
                    if (kt * 16 + hi * 4 + r > ql) s[kt][r] = -1.0e30f;
        }
        // online softmax in log2 domain (Q pre-scaled), defer-max THR=8
        float vm = s[0][0];
#pragma unroll
        for (int kt = 0; kt < 4; kt++)
#pragma unroll
            for (int r = 0; r < 4; r++) vm = fmaxf(vm, s[kt][r]);
        vm = fmaxf(vm, __shfl_xor(vm, 16));
        vm = fmaxf(vm, __shfl_xor(vm, 32));
        if (!__all(vm <= m_run + 8.0f)) {
            float nm = fmaxf(m_run, vm);
            float sc = exp2f(m_run - nm);
            m_run = nm;
            l_part *= sc;
#pragma unroll
            for (int dt = 0; dt < 4; dt++)
#pragma unroll
                for (int r = 0; r < 4; r++) acc[dt][r] *= sc;   // cols=q=lo: lane-local
        }
        float ps = 0.f;
#pragma unroll
        for (int kt = 0; kt < 4; kt++)
#pragma unroll
            for (int r = 0; r < 4; r++) {
                float p = exp2f(s[kt][r] - m_run);
                s[kt][r] = p;
                ps += p;
            }
        l_part += ps;
        // pack P into PV B-fragments (kappa: e<4 -> kv=4hi+e; e>=4 -> 16+4hi+(e-4))
        bf16x8 pa[2];
        {
            union { u16 u[8]; bf16x8 v; } pk0, pk1;
#pragma unroll
            for (int e = 0; e < 4; e++) {
                pk0.u[e]     = f2bf(s[0][e]);
                pk0.u[4 + e] = f2bf(s[1][e]);
                pk1.u[e]     = f2bf(s[2][e]);
                pk1.u[4 + e] = f2bf(s[3][e]);
            }
            pa[0] = pk0.v;
            pa[1] = pk1.v;
        }

        // PV swapped: acc[dt] = mfma(A=V^T frag, B=P) -> C[row=d][col=q=lo]
        const unsigned vtb = ldsb + 8192u + (unsigned)((hi * 64 + lo * 4) * 2);
#pragma unroll
        for (int pr = 0; pr < 2; pr++) {
            u32x2 tv[2][2][2];
#pragma unroll
            for (int d2 = 0; d2 < 2; d2++)
#pragma unroll
                for (int h = 0; h < 2; h++)
#pragma unroll
                    for (int sel = 0; sel < 2; sel++)
                        tv[d2][h][sel] = tr16(vtb + (unsigned)(((h * 4 + pr * 2 + d2) * 512 + sel * 256) * 2));
            asm volatile("s_waitcnt lgkmcnt(0)" ::: "memory");
            __builtin_amdgcn_sched_barrier(0);
            __builtin_amdgcn_s_setprio(1);
#pragma unroll
            for (int d2 = 0; d2 < 2; d2++) {
#pragma unroll
                for (int h = 0; h < 2; h++) {
                    union { unsigned int w[4]; bf16x8 v; } bv;
                    bv.w[0] = tv[d2][h][0][0];
                    bv.w[1] = tv[d2][h][0][1];
                    bv.w[2] = tv[d2][h][1][0];
                    bv.w[3] = tv[d2][h][1][1];
                    acc[pr * 2 + d2] = __builtin_amdgcn_mfma_f32_16x16x32_bf16(bv.v, pa[h], acc[pr * 2 + d2], 0, 0, 0);
                }
            }
            __builtin_amdgcn_s_setprio(0);
        }
    }

    // epilogue: finish l across lane groups (rows of same q), direct stores
    float l = l_part;
    l += __shfl_xor(l, 16);
    l += __shfl_xor(l, 32);
    const float inv = 1.0f / l;
    const int b = bh >> 4, hh = bh & 15;
    const size_t orow = ((size_t)(b * SEQ + qbase + lo)) * 1024 + hh * 64;
#pragma unroll
    for (int dt = 0; dt < 4; dt++) {
        union { u16 u[4]; uint2 d2; } pk;
#pragma unroll
        for (int r = 0; r < 4; r++) pk.u[r] = f2bf(acc[dt][r] * inv);
        *reinterpret_cast<uint2*>(O + orow + dt * 16 + hi * 4) = pk.d2;
    }
}

extern "C" void kernel_launch(void* const* d_in, const int* in_sizes, int n_in,
                              void* d_out, int out_size, void* d_ws, size_t ws_size,
                              hipStream_t stream) {
    const float* x  = (const float*)d_in[0];
    const float* Wq = (const float*)d_in[1];
    const float* Wk = (const float*)d_in[2];
    const float* Wv = (const float*)d_in[3];
    const float* Wo = (const float*)d_in[4];
    const float* bo = (const float*)d_in[5];
    float* out = (float*)d_out;

    char* ws = (char*)d_ws;
    u16* xb  = (u16*)ws;                              // 16 MiB, then weights contiguous
    u16* wqb = (u16*)(ws + 16777216);
    u16* wkb = wqb + 1048576;
    u16* wvb = wkb + 1048576;
    u16* wob = wvb + 1048576;
    u16* q   = (u16*)(ws + 16777216 + 8388608);       // [B][H][N][D] bf16
    u16* k   = q + 8388608;
    u16* v   = k + 8388608;
    u16* ao  = v + 8388608;                           // [B][N][H*64] bf16

    castk_all<<<3072, 256, 0, stream>>>(x, Wq, Wk, Wv, Wo, xb);

    gemm_qkv<<<dim3(ROWS / BM, 24), 256, 0, stream>>>(xb, wqb, wkb, wvb, q, k, v);

    attn<<<dim3(SEQ / 64, BATCH * NUM_HEADS), 256, 0, stream>>>(q, k, v, ao);

    gemm_out<<<dim3(ROWS / BM, MODEL_DIM / BN), 256, 0, stream>>>(ao, wob, out, bo);
}

// Round 7
// 190.491 us; speedup vs baseline: 1.2657x; 1.2657x over previous
//
#include <hip/hip_runtime.h>
#include <hip/hip_bf16.h>

typedef unsigned short u16;
typedef __attribute__((ext_vector_type(8))) __bf16 bf16x8;
typedef __attribute__((ext_vector_type(4))) float f32x4;
typedef __attribute__((ext_vector_type(2))) unsigned int u32x2;

#define MODEL_DIM 1024
#define NUM_HEADS 16
#define HEAD_DIM  64
#define BATCH     4
#define SEQ       2048
#define ROWS      (BATCH*SEQ)     // 8192

static __device__ __forceinline__ u16 f2bf(float f) {
    union { __hip_bfloat16 h; u16 u; } cv;
    cv.h = __float2bfloat16(f);
    return cv.u;
}

static __device__ __forceinline__ void gload16(const u16* g, unsigned lds_byte) {
    __builtin_amdgcn_global_load_lds(
        (const __attribute__((address_space(1))) unsigned int*)g,
        (__attribute__((address_space(3))) unsigned int*)(uintptr_t)lds_byte,
        16, 0, 0);
}

// ---------------- fused cast f32 -> bf16 (x + 4 weights, contiguous out) ----
__global__ void castk_all(const float* __restrict__ x,
                          const float* __restrict__ w0, const float* __restrict__ w1,
                          const float* __restrict__ w2, const float* __restrict__ w3,
                          u16* __restrict__ out) {
    const int total = ROWS * MODEL_DIM + 4 * MODEL_DIM * MODEL_DIM;  // 12.58M
    int i = (blockIdx.x * blockDim.x + threadIdx.x) * 4;
    int stride = gridDim.x * blockDim.x * 4;
    for (; i < total; i += stride) {
        const float* src;
        int off;
        if (i < ROWS * MODEL_DIM) { src = x; off = i; }
        else {
            int j = i - ROWS * MODEL_DIM;
            int w = j >> 20;
            off = j & 1048575;
            src = (w == 0) ? w0 : (w == 1) ? w1 : (w == 2) ? w2 : w3;
        }
        float4 v = *reinterpret_cast<const float4*>(src + off);
        ushort4 o;
        o.x = f2bf(v.x); o.y = f2bf(v.y); o.z = f2bf(v.z); o.w = f2bf(v.w);
        *reinterpret_cast<ushort4*>(out + i) = o;
    }
}

// ---------------- NT GEMM core ----------------
#define BM 128
#define BN 128
#define BK 64
#define LDST 72

// fused QKV projection: grid (M/128, 24); blockIdx.y selects matrix + col block
// Q output is pre-scaled by 0.125*log2(e) (softmax scale folded out of attn).
__global__ __launch_bounds__(256) void gemm_qkv(
    const u16* __restrict__ A,
    const u16* __restrict__ Wq, const u16* __restrict__ Wk, const u16* __restrict__ Wv,
    u16* __restrict__ qO, u16* __restrict__ kO, u16* __restrict__ vO)
{
    __shared__ u16 As[BM * LDST];
    __shared__ u16 Bs[BN * LDST];
    const int t    = threadIdx.x;
    const int wid  = t >> 6;
    const int lane = t & 63;
    const int lo   = lane & 15, hi = lane >> 4;
    const int bm   = blockIdx.x * BM;
    const int mat  = blockIdx.y >> 3;
    const int bn   = (blockIdx.y & 7) * BN;
    const u16* W   = (mat == 0) ? Wq : (mat == 1) ? Wk : Wv;
    u16* outB      = (mat == 0) ? qO : (mat == 1) ? kO : vO;
    const float qscale = (mat == 0) ? 0.18033688f : 1.0f;   // 0.125*log2(e)
    const int wr   = wid >> 1, wc = wid & 1;
    const int K = MODEL_DIM;

    f32x4 acc[4][4];
#pragma unroll
    for (int m = 0; m < 4; m++)
#pragma unroll
        for (int n = 0; n < 4; n++) acc[m][n] = (f32x4){0.f, 0.f, 0.f, 0.f};

    for (int k0 = 0; k0 < K; k0 += BK) {
        __syncthreads();
#pragma unroll
        for (int i = 0; i < 4; i++) {
            int a   = t + 256 * i;
            int row = a >> 3, ch = (a & 7) * 8;
            uint4 va = *reinterpret_cast<const uint4*>(A + (size_t)(bm + row) * K + k0 + ch);
            *reinterpret_cast<uint4*>(As + row * LDST + ch) = va;
            uint4 vb = *reinterpret_cast<const uint4*>(W + (size_t)(bn + row) * K + k0 + ch);
            *reinterpret_cast<uint4*>(Bs + row * LDST + ch) = vb;
        }
        __syncthreads();
#pragma unroll
        for (int h = 0; h < 2; h++) {
            bf16x8 af[4], bfr[4];
#pragma unroll
            for (int m = 0; m < 4; m++)
                af[m] = *reinterpret_cast<const bf16x8*>(As + (wr * 64 + m * 16 + lo) * LDST + h * 32 + hi * 8);
#pragma unroll
            for (int n = 0; n < 4; n++)
                bfr[n] = *reinterpret_cast<const bf16x8*>(Bs + (wc * 64 + n * 16 + lo) * LDST + h * 32 + hi * 8);
#pragma unroll
            for (int m = 0; m < 4; m++)
#pragma unroll
                for (int n = 0; n < 4; n++)
                    acc[m][n] = __builtin_amdgcn_mfma_f32_16x16x32_bf16(af[m], bfr[n], acc[m][n], 0, 0, 0);
        }
    }

#pragma unroll
    for (int m = 0; m < 4; m++)
#pragma unroll
        for (int n = 0; n < 4; n++)
#pragma unroll
            for (int r = 0; r < 4; r++) {
                int row = bm + wr * 64 + m * 16 + hi * 4 + r;
                int col = bn + wc * 64 + n * 16 + lo;
                int b = row >> 11, np = row & 2047;
                int hh = col >> 6, dd = col & 63;
                outB[(((size_t)(b * NUM_HEADS + hh) * SEQ + np) << 6) + dd] = f2bf(acc[m][n][r] * qscale);
            }
}

// out-projection: C = A * Wo^T + bias, f32 out
__global__ __launch_bounds__(256) void gemm_out(
    const u16* __restrict__ A,
    const u16* __restrict__ W,
    float* __restrict__ outF,
    const float* __restrict__ bias)
{
    __shared__ u16 As[BM * LDST];
    __shared__ u16 Bs[BN * LDST];
    const int t    = threadIdx.x;
    const int wid  = t >> 6;
    const int lane = t & 63;
    const int lo   = lane & 15, hi = lane >> 4;
    const int bm   = blockIdx.x * BM;
    const int bn   = blockIdx.y * BN;
    const int wr   = wid >> 1, wc = wid & 1;
    const int K = MODEL_DIM, N = MODEL_DIM;

    f32x4 acc[4][4];
#pragma unroll
    for (int m = 0; m < 4; m++)
#pragma unroll
        for (int n = 0; n < 4; n++) acc[m][n] = (f32x4){0.f, 0.f, 0.f, 0.f};

    for (int k0 = 0; k0 < K; k0 += BK) {
        __syncthreads();
#pragma unroll
        for (int i = 0; i < 4; i++) {
            int a   = t + 256 * i;
            int row = a >> 3, ch = (a & 7) * 8;
            uint4 va = *reinterpret_cast<const uint4*>(A + (size_t)(bm + row) * K + k0 + ch);
            *reinterpret_cast<uint4*>(As + row * LDST + ch) = va;
            uint4 vb = *reinterpret_cast<const uint4*>(W + (size_t)(bn + row) * K + k0 + ch);
            *reinterpret_cast<uint4*>(Bs + row * LDST + ch) = vb;
        }
        __syncthreads();
#pragma unroll
        for (int h = 0; h < 2; h++) {
            bf16x8 af[4], bfr[4];
#pragma unroll
            for (int m = 0; m < 4; m++)
                af[m] = *reinterpret_cast<const bf16x8*>(As + (wr * 64 + m * 16 + lo) * LDST + h * 32 + hi * 8);
#pragma unroll
            for (int n = 0; n < 4; n++)
                bfr[n] = *reinterpret_cast<const bf16x8*>(Bs + (wc * 64 + n * 16 + lo) * LDST + h * 32 + hi * 8);
#pragma unroll
            for (int m = 0; m < 4; m++)
#pragma unroll
                for (int n = 0; n < 4; n++)
                    acc[m][n] = __builtin_amdgcn_mfma_f32_16x16x32_bf16(af[m], bfr[n], acc[m][n], 0, 0, 0);
        }
    }

#pragma unroll
    for (int m = 0; m < 4; m++)
#pragma unroll
        for (int n = 0; n < 4; n++)
#pragma unroll
            for (int r = 0; r < 4; r++) {
                int row = bm + wr * 64 + m * 16 + hi * 4 + r;
                int col = bn + wc * 64 + n * 16 + lo;
                outF[(size_t)row * N + col] = acc[m][n][r] + bias[col];
            }
}

// ---------------- flash attention v6 -------------------------------------
// v5 internals unchanged. New 1D block map (model: CU = blockIdx mod 256):
//  - bh = (slot&7)*8 + (g&7): all 32 q-tiles of a head share one XCD ->
//    its 512KB KV stays in that XCD's L2 (8 bh x 512KB = 4MB L2).
//  - qt balanced: CU's 8 blocks get qt-sets {a0,7-a0+4,...} with
//    sum(qt+1) = 132 for EVERY CU (exact balance, no drain tail).

static __device__ __forceinline__ u32x2 tr16(unsigned int addr) {
    u32x2 r;
    asm volatile("ds_read_b64_tr_b16 %0, %1" : "=v"(r) : "v"(addr));
    return r;
}

__global__ __launch_bounds__(256, 8) void attn(
    const u16* __restrict__ Q,   // [B*H][N][64]
    const u16* __restrict__ Kg,
    const u16* __restrict__ Vg,
    u16* __restrict__ O)         // [B][N][H*64]
{
    // LDS (u16 elems): K swizzled @0 (4096), V subtiled @4096 (4096) = 16KB
    __shared__ u16 lds[8192];
    const int t    = threadIdx.x;
    const int wid  = t >> 6, lane = t & 63;
    const int lo   = lane & 15, hi = lane >> 4;

    const int g    = blockIdx.x;             // 0..2047
    const int slot = g >> 3;                 // 0..255
    const int bh   = ((slot & 7) << 3) + (g & 7);
    const int a    = slot >> 3;              // 0..31
    const int u    = a >> 2, a0 = a & 3;
    const int qt   = 4 * u + ((u & 1) ? 3 - a0 : a0);

    const size_t base = (size_t)bh * SEQ * 64;
    const int qbase = qt * 64 + wid * 16;
    const unsigned ldsb = (unsigned)(uintptr_t)lds;

    // staging: per-lane global source offsets for linear LDS dests.
    // K swizzled: LDS slot o holds K[o>>6][ ((((o&63)*2) ^ ((o>>6 & 7)<<4))) >> 1 ]
    // V subtiled: slot o holds V[(o>>11)*32 + ((o>>4)&31)][((o>>9)&3)*16 + (o&15)]
    int srcK[2], srcV[2];
    unsigned dstK[2], dstV[2];
#pragma unroll
    for (int ti = 0; ti < 2; ti++) {
        int o   = t * 8 + ti * 2048;
        int row = o >> 6;
        int colb = ((o & 63) * 2) ^ ((row & 7) << 4);
        srcK[ti] = row * 64 + (colb >> 1);
        dstK[ti] = ldsb + o * 2;
        int st = o >> 9;
        int kv = (st >> 2) * 32 + ((o >> 4) & 31);
        int d  = (st & 3) * 16 + (o & 15);
        srcV[ti] = kv * 64 + d;
        dstV[ti] = ldsb + 8192 + o * 2;
    }

    // Q fragments (B-operand): lane holds Q[qbase+lo][h*32+hi*8+..] (pre-scaled)
    bf16x8 qf[2];
#pragma unroll
    for (int h = 0; h < 2; h++)
        qf[h] = *reinterpret_cast<const bf16x8*>(Q + base + (size_t)(qbase + lo) * 64 + h * 32 + hi * 8);
    asm volatile("" : "+v"(qf[0]), "+v"(qf[1]));

    float m_run = -3.0e38f, l_part = 0.f;
    f32x4 acc[4];
#pragma unroll
    for (int dt = 0; dt < 4; dt++) acc[dt] = (f32x4){0.f, 0.f, 0.f, 0.f};

    for (int j = 0; j <= qt; j++) {
        __builtin_amdgcn_s_barrier();       // prev-iter readers done before overwrite
        {
            const u16* Kt = Kg + base + (size_t)j * 4096;
            const u16* Vt = Vg + base + (size_t)j * 4096;
#pragma unroll
            for (int ti = 0; ti < 2; ti++) {
                gload16(Kt + srcK[ti], dstK[ti]);
                gload16(Vt + srcV[ti], dstV[ti]);
            }
        }
        asm volatile("s_waitcnt vmcnt(0)" ::: "memory");
        __builtin_amdgcn_s_barrier();
        __builtin_amdgcn_sched_barrier(0);

        // S^T = K Q^T: lane holds S[q=qbase+lo][kv=j*64+kt*16+hi*4+r]
        f32x4 s[4];
#pragma unroll
        for (int kh = 0; kh < 2; kh++) {    // kt halves: caps kf live-set at 16 VGPR
            bf16x8 kfa[2][2];
#pragma unroll
            for (int k2 = 0; k2 < 2; k2++)
#pragma unroll
                for (int h = 0; h < 2; h++)
                    kfa[k2][h] = *reinterpret_cast<const bf16x8*>(
                        (const char*)lds + ((kh * 2 + k2) * 16 + lo) * 128 + ((h * 64 + hi * 16) ^ ((lo & 7) << 4)));
            __builtin_amdgcn_s_setprio(1);
#pragma unroll
            for (int k2 = 0; k2 < 2; k2++) {
                f32x4 a2 = (f32x4){0.f, 0.f, 0.f, 0.f};
#pragma unroll
                for (int h = 0; h < 2; h++)
                    a2 = __builtin_amdgcn_mfma_f32_16x16x32_bf16(kfa[k2][h], qf[h], a2, 0, 0, 0);
                s[kh * 2 + k2] = a2;
            }
            __builtin_amdgcn_s_setprio(0);
        }
        if (j == qt) {                       // diagonal: causal mask (local indices)
            const int ql = wid * 16 + lo;
#pragma unroll
            for (int kt = 0; kt < 4; kt++)
#pragma unroll
                for (int r = 0; r < 4; r++)
                    if (kt * 16 + hi * 4 + r > ql) s[kt][r] = -1.0e30f;
        }
        // online softmax in log2 domain (Q pre-scaled), defer-max THR=8
        float vm = s[0][0];
#pragma unroll
        for (int kt = 0; kt < 4; kt++)
#pragma unroll
            for (int r = 0; r < 4; r++) vm = fmaxf(vm, s[kt][r]);
        vm = fmaxf(vm, __shfl_xor(vm, 16));
        vm = fmaxf(vm, __shfl_xor(vm, 32));
        if (!__all(vm <= m_run + 8.0f)) {
            float nm = fmaxf(m_run, vm);
            float sc = exp2f(m_run - nm);
            m_run = nm;
            l_part *= sc;
#pragma unroll
            for (int dt = 0; dt < 4; dt++)
#pragma unroll
                for (int r = 0; r < 4; r++) acc[dt][r] *= sc;   // cols=q=lo: lane-local
        }
        float ps = 0.f;
#pragma unroll
        for (int kt = 0; kt < 4; kt++)
#pragma unroll
            for (int r = 0; r < 4; r++) {
                float p = exp2f(s[kt][r] - m_run);
                s[kt][r] = p;
                ps += p;
            }
        l_part += ps;
        // pack P into PV B-fragments (kappa: e<4 -> kv=4hi+e; e>=4 -> 16+4hi+(e-4))
        bf16x8 pa[2];
        {
            union { u16 uu[8]; bf16x8 v; } pk0, pk1;
#pragma unroll
            for (int e = 0; e < 4; e++) {
                pk0.uu[e]     = f2bf(s[0][e]);
                pk0.uu[4 + e] = f2bf(s[1][e]);
                pk1.uu[e]     = f2bf(s[2][e]);
                pk1.uu[4 + e] = f2bf(s[3][e]);
            }
            pa[0] = pk0.v;
            pa[1] = pk1.v;
        }

        // PV swapped: acc[dt] = mfma(A=V^T frag, B=P) -> C[row=d][col=q=lo]
        const unsigned vtb = ldsb + 8192u + (unsigned)((hi * 64 + lo * 4) * 2);
#pragma unroll
        for (int pr = 0; pr < 2; pr++) {
            u32x2 tv[2][2][2];
#pragma unroll
            for (int d2 = 0; d2 < 2; d2++)
#pragma unroll
                for (int h = 0; h < 2; h++)
#pragma unroll
                    for (int sel = 0; sel < 2; sel++)
                        tv[d2][h][sel] = tr16(vtb + (unsigned)(((h * 4 + pr * 2 + d2) * 512 + sel * 256) * 2));
            asm volatile("s_waitcnt lgkmcnt(0)" ::: "memory");
            __builtin_amdgcn_sched_barrier(0);
            __builtin_amdgcn_s_setprio(1);
#pragma unroll
            for (int d2 = 0; d2 < 2; d2++) {
#pragma unroll
                for (int h = 0; h < 2; h++) {
                    union { unsigned int w[4]; bf16x8 v; } bv;
                    bv.w[0] = tv[d2][h][0][0];
                    bv.w[1] = tv[d2][h][0][1];
                    bv.w[2] = tv[d2][h][1][0];
                    bv.w[3] = tv[d2][h][1][1];
                    acc[pr * 2 + d2] = __builtin_amdgcn_mfma_f32_16x16x32_bf16(bv.v, pa[h], acc[pr * 2 + d2], 0, 0, 0);
                }
            }
            __builtin_amdgcn_s_setprio(0);
        }
    }

    // epilogue: finish l across lane groups (rows of same q), direct stores
    float l = l_part;
    l += __shfl_xor(l, 16);
    l += __shfl_xor(l, 32);
    const float inv = 1.0f / l;
    const int b = bh >> 4, hh = bh & 15;
    const size_t orow = ((size_t)(b * SEQ + qbase + lo)) * 1024 + hh * 64;
#pragma unroll
    for (int dt = 0; dt < 4; dt++) {
        union { u16 uu[4]; uint2 d2; } pk;
#pragma unroll
        for (int r = 0; r < 4; r++) pk.uu[r] = f2bf(acc[dt][r] * inv);
        *reinterpret_cast<uint2*>(O + orow + dt * 16 + hi * 4) = pk.d2;
    }
}

extern "C" void kernel_launch(void* const* d_in, const int* in_sizes, int n_in,
                              void* d_out, int out_size, void* d_ws, size_t ws_size,
                              hipStream_t stream) {
    const float* x  = (const float*)d_in[0];
    const float* Wq = (const float*)d_in[1];
    const float* Wk = (const float*)d_in[2];
    const float* Wv = (const float*)d_in[3];
    const float* Wo = (const float*)d_in[4];
    const float* bo = (const float*)d_in[5];
    float* out = (float*)d_out;

    char* ws = (char*)d_ws;
    u16* xb  = (u16*)ws;                              // 16 MiB, then weights contiguous
    u16* wqb = (u16*)(ws + 16777216);
    u16* wkb = wqb + 1048576;
    u16* wvb = wkb + 1048576;
    u16* wob = wvb + 1048576;
    u16* q   = (u16*)(ws + 16777216 + 8388608);       // [B][H][N][D] bf16
    u16* k   = q + 8388608;
    u16* v   = k + 8388608;
    u16* ao  = v + 8388608;                           // [B][N][H*64] bf16

    castk_all<<<3072, 256, 0, stream>>>(x, Wq, Wk, Wv, Wo, xb);

    gemm_qkv<<<dim3(ROWS / BM, 24), 256, 0, stream>>>(xb, wqb, wkb, wvb, q, k, v);

    attn<<<2048, 256, 0, stream>>>(q, k, v, ao);

    gemm_out<<<dim3(ROWS / BM, MODEL_DIM / BN), 256, 0, stream>>>(ao, wob, out, bo);
}